// Round 3
// baseline (1993.692 us; speedup 1.0000x reference)
//
#include <hip/hip_runtime.h>
#include <hip/hip_bf16.h>
#include <math.h>

typedef float f32x4 __attribute__((ext_vector_type(4)));
typedef __bf16 bf16x8 __attribute__((ext_vector_type(8)));

#define T_N 64
#define HW_N 729
#define HW_PV 768       /* padded hw for Vt: 12 full kv-tiles of 64 */
#define M_N 512
#define DM 1152
#define NH 8
#define DH 144
#define MQ 32768        /* T*M rows */
#define MK 46656        /* T*HW rows */
#define MK_PAD 46720    /* padded to multiple of 128 (365 tiles) */

// ---- workspace layout (bytes); Vt overlays feat_bf (dead after K-proj) ----
#define SZ_FEAT ((size_t)MK_PAD * DM * 2)
#define SZ_VT   ((size_t)T_N * NH * DH * HW_PV * 2)
#define SZ_OV   (SZ_VT > SZ_FEAT ? SZ_VT : SZ_FEAT)
#define SZ_Q    ((size_t)MQ * DM * 2)
#define SZ_W    ((size_t)DM * DM * 2)
#define OFF_KN   ((size_t)0)
#define OFF_TOK  (OFF_KN + SZ_FEAT)
#define OFF_QN   (OFF_TOK + SZ_Q)
#define OFF_OV   (OFF_QN + SZ_Q)
#define OFF_WT   (OFF_OV + SZ_OV)
#define WS_NEED  (OFF_WT + 3 * SZ_W)

// async global->LDS 16B (wave-uniform base + lane*16 placement)
__device__ __forceinline__ void async_copy16(void* lds, const void* g) {
    __builtin_amdgcn_global_load_lds(
        (const __attribute__((address_space(1))) void*)g,
        (__attribute__((address_space(3))) void*)lds, 16, 0, 0);
}

// ---------------- fp32 -> bf16 convert (with zero padding) ----------------
__global__ __launch_bounds__(256) void cvt_bf16(const float* __restrict__ src,
                                                __bf16* __restrict__ dst,
                                                long valid4, long total4) {
    long i = (long)blockIdx.x * 256 + threadIdx.x;
    if (i >= total4) return;
    float4 f = {0.f, 0.f, 0.f, 0.f};
    if (i < valid4) f = ((const float4*)src)[i];
    __bf16 tmp[4] = {(__bf16)f.x, (__bf16)f.y, (__bf16)f.z, (__bf16)f.w};
    *((uint2*)(dst + i * 4)) = *((uint2*)tmp);
}

// ---------------- W [K][N] fp32 -> Wt [N][K] bf16 ----------------
__global__ __launch_bounds__(256) void transpose_w(const float* __restrict__ W,
                                                   __bf16* __restrict__ Wt) {
    __shared__ float tile[32][33];
    const int k0 = blockIdx.x * 32, n0 = blockIdx.y * 32;
    const int tx = threadIdx.x, ty = threadIdx.y; // 32 x 8
    #pragma unroll
    for (int i = 0; i < 32; i += 8)
        tile[ty + i][tx] = W[(long)(k0 + ty + i) * DM + n0 + tx];
    __syncthreads();
    #pragma unroll
    for (int i = 0; i < 32; i += 8)
        Wt[(long)(n0 + ty + i) * DM + k0 + tx] = (__bf16)tile[tx][ty + i];
}

// ---- V transpose: features fp32 [t][hw][1152] -> Vt bf16 [t*8+h][dh 144][col 768]
// column order PERMUTED within each 64-kv tile so attn's in-register P^T
// (from swapped QK^T) feeds the PV mfma B-operand directly.
// hw-offset bits [5]=kh,[4]=b,[3:2]=q,[1:0]=jj  ->  col bits [5]=kh,[4:3]=q,[2]=b,[1:0]=jj:
//   col(hw) = (hw & ~31) | ((hw>>2 & 3)<<3) | ((hw>>4 & 1)<<2) | (hw & 3)
__global__ __launch_bounds__(256) void transpose_v(const float* __restrict__ f,
                                                   __bf16* __restrict__ vt) {
    __shared__ float tile[32][149];
    const int hw0 = blockIdx.x * 32, h = blockIdx.y, t = blockIdx.z;
    const int tid = threadIdx.x;
    for (int c = tid; c < 32 * 36; c += 256) {
        const int r = c / 36, s = c % 36;
        const int hw = hw0 + r;
        float4 v = {0.f, 0.f, 0.f, 0.f};
        if (hw < HW_N) v = *(const float4*)(f + ((long)t * HW_N + hw) * DM + h * DH + s * 4);
        tile[r][s * 4 + 0] = v.x; tile[r][s * 4 + 1] = v.y;
        tile[r][s * 4 + 2] = v.z; tile[r][s * 4 + 3] = v.w;
    }
    __syncthreads();
    for (int c = tid; c < DH * 8; c += 256) {   // 144 d-rows x 8 granules of 4 hw
        const int d = c >> 3, g = c & 7;
        const int base4 = hw0 + g * 4;          // 4 consecutive hw, base4 % 4 == 0
        const int cb = (base4 & ~31) | (((base4 >> 2) & 3) << 3) | (((base4 >> 4) & 1) << 2);
        __bf16 tmp[4];
        #pragma unroll
        for (int i = 0; i < 4; ++i) tmp[i] = (__bf16)tile[g * 4 + i][d];
        *(uint2*)(vt + ((long)(t * NH + h) * DH + d) * HW_PV + cb) = *(uint2*)tmp;
    }
}

// ---------------- bf16 MFMA GEMM: C[M,N] = A[M,K] * Bt[N,K]^T ----------------
// 128x128 tile, BK=32, global_load_lds staging + XOR slot swizzle (conflict-free)
template<bool STORE_BF16>
__global__ __launch_bounds__(256) void gemm_bt(const __bf16* __restrict__ A,
                                               const __bf16* __restrict__ Bt,
                                               void* __restrict__ Cout) {
    __shared__ __align__(16) __bf16 As[128 * 32];
    __shared__ __align__(16) __bf16 Bs[128 * 32];
    const int tid  = threadIdx.x;
    const int wave = tid >> 6, lane = tid & 63;
    const int quad = lane >> 4, l16 = lane & 15;
    const int wr = wave >> 1, wc = wave & 1;
    const long m0 = (long)blockIdx.x * 128;
    const long n0 = (long)blockIdx.y * 128;
    const int swzr = quad ^ ((l16 >> 1) & 3);   // frag-read slot swizzle
    f32x4 acc[4][4] = {};
    for (int kt = 0; kt < 36; ++kt) {
        const int k0 = kt * 32;
        __syncthreads();
        #pragma unroll
        for (int s = 0; s < 2; ++s) {
            const int c = s * 256 + tid;        // 512 chunks of 16B each matrix
            const int row = c >> 2;
            const int gkc = (c & 3) ^ ((c >> 3) & 3);   // slot->global kc swizzle
            async_copy16(As + c * 8, A  + (m0 + row) * DM + k0 + gkc * 8);
            async_copy16(Bs + c * 8, Bt + (n0 + row) * DM + k0 + gkc * 8);
        }
        __syncthreads();
        bf16x8 af[4], bfr[4];
        #pragma unroll
        for (int i = 0; i < 4; ++i)
            af[i] = *(const bf16x8*)(As + (wr * 64 + i * 16 + l16) * 32 + swzr * 8);
        #pragma unroll
        for (int j = 0; j < 4; ++j)
            bfr[j] = *(const bf16x8*)(Bs + (wc * 64 + j * 16 + l16) * 32 + swzr * 8);
        #pragma unroll
        for (int i = 0; i < 4; ++i)
            #pragma unroll
            for (int j = 0; j < 4; ++j)
                acc[i][j] = __builtin_amdgcn_mfma_f32_16x16x32_bf16(af[i], bfr[j], acc[i][j], 0, 0, 0);
    }
    #pragma unroll
    for (int i = 0; i < 4; ++i) {
        #pragma unroll
        for (int j = 0; j < 4; ++j) {
            #pragma unroll
            for (int r = 0; r < 4; ++r) {
                const long row = m0 + wr * 64 + i * 16 + quad * 4 + r;
                const long col = n0 + wc * 64 + j * 16 + l16;
                if constexpr (STORE_BF16)
                    ((__bf16*)Cout)[row * DM + col] = (__bf16)acc[i][j][r];
                else
                    ((float*)Cout)[row * DM + col] = acc[i][j][r];
            }
        }
    }
}

// ---------------- LayerNorm (no bias) over 1152, in-place bf16 ----------------
__global__ __launch_bounds__(256) void ln_q(__bf16* __restrict__ Q, const float* __restrict__ w) {
    const long row = blockIdx.x;
    __bf16* p = Q + row * DM;
    const int tid = threadIdx.x;
    float v[5];
    int nv = 0;
    float s = 0.f, s2 = 0.f;
    for (int i = tid; i < DM; i += 256) {
        float x = (float)p[i];
        v[nv++] = x; s += x; s2 += x * x;
    }
    #pragma unroll
    for (int o = 32; o > 0; o >>= 1) { s += __shfl_down(s, o); s2 += __shfl_down(s2, o); }
    __shared__ float red[8];
    if ((tid & 63) == 0) { red[tid >> 6] = s; red[4 + (tid >> 6)] = s2; }
    __syncthreads();
    const float S  = red[0] + red[1] + red[2] + red[3];
    const float S2 = red[4] + red[5] + red[6] + red[7];
    const float mu  = S * (1.f / DM);
    const float var = S2 * (1.f / DM) - mu * mu;
    const float rstd = rsqrtf(var + 1e-6f);
    nv = 0;
    for (int i = tid; i < DM; i += 256)
        p[i] = (__bf16)((v[nv++] - mu) * rstd * w[i]);
}

// ---------------- RoPE-2D (full 1152 dim) + LayerNorm, in-place bf16 ----------------
__global__ __launch_bounds__(256) void rope_ln_k(__bf16* __restrict__ K,
                                                 const float* __restrict__ fpos,
                                                 const float* __restrict__ w) {
    const long row = blockIdx.x;            // 0..46655 = t*729+hw
    const int hw = (int)(row % HW_N);
    const float px = fpos[hw * 2 + 0];
    const float py = fpos[hw * 2 + 1];
    __bf16* p = K + row * DM;
    __shared__ float buf[DM];
    __shared__ float red[8];
    const int tid = threadIdx.x;
    float s = 0.f, s2 = 0.f;
    for (int pr = tid; pr < 576; pr += 256) {   // 288 x-pairs then 288 y-pairs
        const bool isx = pr < 288;
        const int  i   = isx ? pr : pr - 288;
        const int  off = isx ? 2 * i : 576 + 2 * i;
        const float pos = isx ? px : py;
        const float theta = exp2f((float)i * -0.046137890206768924f); // 10000^(-i/288)
        float sn, cs;
        sincosf(pos * theta, &sn, &cs);
        const float a = (float)p[off], b = (float)p[off + 1];
        const float o1 = a * cs - b * sn;
        const float o2 = a * sn + b * cs;
        buf[off] = o1; buf[off + 1] = o2;
        s += o1 + o2; s2 += o1 * o1 + o2 * o2;
    }
    #pragma unroll
    for (int o = 32; o > 0; o >>= 1) { s += __shfl_down(s, o); s2 += __shfl_down(s2, o); }
    if ((tid & 63) == 0) { red[tid >> 6] = s; red[4 + (tid >> 6)] = s2; }
    __syncthreads();
    const float S  = red[0] + red[1] + red[2] + red[3];
    const float S2 = red[4] + red[5] + red[6] + red[7];
    const float mu  = S * (1.f / DM);
    const float var = S2 * (1.f / DM) - mu * mu;
    const float rstd = rsqrtf(var + 1e-6f);
    for (int i = tid; i < DM; i += 256)
        p[i] = (__bf16)((buf[i] - mu) * rstd * w[i]);
}

// ---------------- flash attention + gaussian spatial bias (barrier-free) ----------------
// Swapped-operand QK^T (S^T in regs) -> in-register softmax (2 shfl/row-reduce)
// -> P packed lane-locally as PV B-frags (V columns pre-permuted in Vt).
// No LDS, no __syncthreads. XCD swizzle: 4 qt-blocks of one (t,h) share an XCD.
__global__ __launch_bounds__(256, 3) void attn(const __bf16* __restrict__ Qn,
                                               const __bf16* __restrict__ Kn,
                                               const __bf16* __restrict__ Vt,
                                               const float* __restrict__ tracks,
                                               const float* __restrict__ fpos,
                                               __bf16* __restrict__ Out) {
    const int i  = blockIdx.x;
    const int g  = ((i >> 5) << 3) | (i & 7);   // (t,h) group 0..511
    const int qt = (i >> 3) & 3;                // q-tile 0..3
    const int h  = g & 7, t = g >> 3;
    const int tid = threadIdx.x;
    const int wave = tid >> 6, lane = tid & 63;
    const int quad = lane >> 4, l16 = lane & 15;
    const int wq = wave * 32;                   // wave's q-row base within block

    const __bf16* qb = Qn + ((long)t * M_N + qt * 128 + wq) * DM + h * DH;
    const __bf16* kb = Kn + (long)t * HW_N * DM + h * DH;
    const __bf16* vb = Vt + (long)(t * NH + h) * DH * HW_PV;

    // per-lane track (this lane's q-row = l16 within each rt tile)
    float tx[2], ty[2];
    #pragma unroll
    for (int rt = 0; rt < 2; ++rt) {
        const float2 tr = ((const float2*)tracks)[(long)t * M_N + qt * 128 + wq + rt * 16 + l16];
        tx[rt] = tr.x; ty[rt] = tr.y;
    }

    f32x4 Ot[2][9] = {};
    float mrow[2] = {-1e30f, -1e30f}, lrow[2] = {0.f, 0.f};

    for (int kt = 0; kt < 12; ++kt) {
        const int kv0 = kt * 64;
        // --- S^T = (K Q^T): sc[rt][jt] tile [kv 16][q 16]; lane col=q(l16), row=kv(quad*4+r)
        f32x4 sc[2][4] = {};
        #pragma unroll
        for (int kc = 0; kc < 5; ++kc) {
            bf16x8 bq[2];
            #pragma unroll
            for (int rt = 0; rt < 2; ++rt) {
                uint4 u = {0u, 0u, 0u, 0u};
                if (kc < 4 || quad < 2)
                    u = *(const uint4*)(qb + (long)(rt * 16 + l16) * DM + kc * 32 + quad * 8);
                bq[rt] = *(bf16x8*)&u;
            }
            #pragma unroll
            for (int jt = 0; jt < 4; ++jt) {
                const bf16x8 ak = *(const bf16x8*)(kb + (long)(kv0 + jt * 16 + l16) * DM + kc * 32 + quad * 8);
                #pragma unroll
                for (int rt = 0; rt < 2; ++rt)
                    sc[rt][jt] = __builtin_amdgcn_mfma_f32_16x16x32_bf16(ak, bq[rt], sc[rt][jt], 0, 0, 0);
            }
        }
        // --- gaussian bias + mask (lane kv = kv0 + jt*16 + quad*4 + r) ---
        #pragma unroll
        for (int jt = 0; jt < 4; ++jt) {
            const int kvb = kv0 + jt * 16 + quad * 4;
            float2 fp[4];
            if (kvb + 3 < HW_N) {
                const float4 a  = *(const float4*)(fpos + (long)kvb * 2);
                const float4 b2 = *(const float4*)(fpos + (long)kvb * 2 + 4);
                fp[0] = {a.x, a.y};  fp[1] = {a.z, a.w};
                fp[2] = {b2.x, b2.y}; fp[3] = {b2.z, b2.w};
            } else {
                #pragma unroll
                for (int r = 0; r < 4; ++r) {
                    const int k2 = (kvb + r < HW_N) ? kvb + r : HW_N - 1;
                    fp[r] = ((const float2*)fpos)[k2];
                }
            }
            #pragma unroll
            for (int rt = 0; rt < 2; ++rt)
                #pragma unroll
                for (int r = 0; r < 4; ++r) {
                    const float dx = tx[rt] - fp[r].x, dy = ty[rt] - fp[r].y;
                    float v = sc[rt][jt][r] * (1.f / 12.f) - (dx * dx + dy * dy) * 0.125f;
                    if (kvb + r >= HW_N) v = -1e30f;
                    sc[rt][jt][r] = v;
                }
        }
        // --- online softmax (per-lane row; cross-quad via 2 shfl) ---
        #pragma unroll
        for (int rt = 0; rt < 2; ++rt) {
            float mp = -1e30f;
            #pragma unroll
            for (int jt = 0; jt < 4; ++jt)
                #pragma unroll
                for (int r = 0; r < 4; ++r) mp = fmaxf(mp, sc[rt][jt][r]);
            mp = fmaxf(mp, __shfl_xor(mp, 16));
            mp = fmaxf(mp, __shfl_xor(mp, 32));
            const float mn = fmaxf(mrow[rt], mp);
            const float al = __expf(mrow[rt] - mn);
            mrow[rt] = mn;
            float rs = 0.f;
            #pragma unroll
            for (int jt = 0; jt < 4; ++jt)
                #pragma unroll
                for (int r = 0; r < 4; ++r) {
                    const float p = __expf(sc[rt][jt][r] - mn);
                    sc[rt][jt][r] = p;
                    rs += p;
                }
            rs += __shfl_xor(rs, 16);
            rs += __shfl_xor(rs, 32);
            lrow[rt] = lrow[rt] * al + rs;
            #pragma unroll
            for (int d = 0; d < 9; ++d) Ot[rt][d] *= al;
        }
        // --- O^T += V^T P^T: B-frag is lane-local pack of P (V cols pre-permuted) ---
        #pragma unroll
        for (int kh = 0; kh < 2; ++kh) {
            bf16x8 bp[2];
            #pragma unroll
            for (int rt = 0; rt < 2; ++rt) {
                __bf16 tmp[8];
                #pragma unroll
                for (int j = 0; j < 4; ++j) {
                    tmp[j]     = (__bf16)sc[rt][2 * kh][j];
                    tmp[4 + j] = (__bf16)sc[rt][2 * kh + 1][j];
                }
                bp[rt] = *(bf16x8*)tmp;
            }
            #pragma unroll
            for (int dt = 0; dt < 9; ++dt) {
                const bf16x8 av = *(const bf16x8*)(vb + (long)(dt * 16 + l16) * HW_PV + kv0 + kh * 32 + quad * 8);
                #pragma unroll
                for (int rt = 0; rt < 2; ++rt)
                    Ot[rt][dt] = __builtin_amdgcn_mfma_f32_16x16x32_bf16(av, bp[rt], Ot[rt][dt], 0, 0, 0);
            }
        }
    }
    // epilogue: lane holds O^T cols q=l16; d = dt*16 + quad*4 + r -> 8B stores
    #pragma unroll
    for (int rt = 0; rt < 2; ++rt) {
        const float inv = 1.f / lrow[rt];
        const long row = (long)t * M_N + qt * 128 + wq + rt * 16 + l16;
        #pragma unroll
        for (int dt = 0; dt < 9; ++dt) {
            __bf16 o4[4];
            #pragma unroll
            for (int r = 0; r < 4; ++r) o4[r] = (__bf16)(Ot[rt][dt][r] * inv);
            *(uint2*)(Out + row * DM + h * DH + dt * 16 + quad * 4) = *(uint2*)o4;
        }
    }
}

extern "C" void kernel_launch(void* const* d_in, const int* in_sizes, int n_in,
                              void* d_out, int out_size, void* d_ws, size_t ws_size,
                              hipStream_t stream) {
    const float* features = (const float*)d_in[0];
    const float* tracks   = (const float*)d_in[1];
    const float* tok      = (const float*)d_in[2];
    const float* fpos     = (const float*)d_in[3];
    const float* W_q      = (const float*)d_in[4];
    const float* W_k      = (const float*)d_in[5];
    const float* q_w      = (const float*)d_in[6];
    const float* k_w      = (const float*)d_in[7];
    const float* W_o      = (const float*)d_in[8];

    if (ws_size < WS_NEED) return; // failure signature: absmax == max|ref|

    char* ws = (char*)d_ws;
    __bf16* kn      = (__bf16*)(ws + OFF_KN);
    __bf16* tok_bf  = (__bf16*)(ws + OFF_TOK);  // reused as `sampled` after Q-proj
    __bf16* qn      = (__bf16*)(ws + OFF_QN);
    __bf16* feat_bf = (__bf16*)(ws + OFF_OV);   // overlay: feat_bf then Vt
    __bf16* vt      = (__bf16*)(ws + OFF_OV);
    __bf16* wt_q    = (__bf16*)(ws + OFF_WT);
    __bf16* wt_k    = (__bf16*)(ws + OFF_WT + SZ_W);
    __bf16* wt_o    = (__bf16*)(ws + OFF_WT + 2 * SZ_W);

    // converts (features zero-padded to MK_PAD rows)
    {
        const long valid4 = (long)MK * DM / 4, total4 = (long)MK_PAD * DM / 4;
        cvt_bf16<<<(int)((total4 + 255) / 256), 256, 0, stream>>>(features, feat_bf, valid4, total4);
    }
    {
        const long n4 = (long)MQ * DM / 4;
        cvt_bf16<<<(int)((n4 + 255) / 256), 256, 0, stream>>>(tok, tok_bf, n4, n4);
    }
    // weight transposes
    dim3 tb(32, 8);
    transpose_w<<<dim3(36, 36), tb, 0, stream>>>(W_q, wt_q);
    transpose_w<<<dim3(36, 36), tb, 0, stream>>>(W_k, wt_k);
    transpose_w<<<dim3(36, 36), tb, 0, stream>>>(W_o, wt_o);

    // projections
    gemm_bt<true><<<dim3(MQ / 128, DM / 128), 256, 0, stream>>>(tok_bf, wt_q, qn);
    gemm_bt<true><<<dim3(MK_PAD / 128, DM / 128), 256, 0, stream>>>(feat_bf, wt_k, kn);

    // norms (+RoPE for K)
    ln_q<<<MQ, 256, 0, stream>>>(qn, q_w);
    rope_ln_k<<<MK, 256, 0, stream>>>(kn, fpos, k_w);

    // V transpose (overwrites feat_bf overlay — feat_bf dead after K-proj)
    transpose_v<<<dim3(HW_PV / 32, NH, T_N), 256, 0, stream>>>(features, vt);

    // attention -> sampled (reuses tok_bf region)
    __bf16* sampled = tok_bf;
    attn<<<T_N * NH * (M_N / 128), 256, 0, stream>>>(qn, kn, vt, tracks, fpos, sampled);

    // output projection -> d_out (fp32)
    gemm_bt<false><<<dim3(MQ / 128, DM / 128), 256, 0, stream>>>(sampled, wt_o, d_out);
}

// Round 4
// 1971.331 us; speedup vs baseline: 1.0113x; 1.0113x over previous
//
#include <hip/hip_runtime.h>
#include <hip/hip_bf16.h>
#include <math.h>

typedef float f32x4 __attribute__((ext_vector_type(4)));
typedef __bf16 bf16x8 __attribute__((ext_vector_type(8)));

#define T_N 64
#define HW_N 729
#define HW_PV 768       /* padded hw for Vt: 12 full kv-tiles of 64 */
#define M_N 512
#define DM 1152
#define NH 8
#define DH 144
#define MQ 32768        /* T*M rows */
#define MK 46656        /* T*HW rows */
#define MK_PAD 46720    /* padded to multiple of 128 (365 tiles) */

// ---- workspace layout (bytes); Vt overlays feat_bf (dead after K-proj) ----
#define SZ_FEAT ((size_t)MK_PAD * DM * 2)
#define SZ_VT   ((size_t)T_N * NH * DH * HW_PV * 2)
#define SZ_OV   (SZ_VT > SZ_FEAT ? SZ_VT : SZ_FEAT)
#define SZ_Q    ((size_t)MQ * DM * 2)
#define SZ_W    ((size_t)DM * DM * 2)
#define OFF_KN   ((size_t)0)
#define OFF_TOK  (OFF_KN + SZ_FEAT)
#define OFF_QN   (OFF_TOK + SZ_Q)
#define OFF_OV   (OFF_QN + SZ_Q)
#define OFF_WT   (OFF_OV + SZ_OV)
#define WS_NEED  (OFF_WT + 3 * SZ_W)

// async global->LDS 16B (wave-uniform base + lane*16 placement)
__device__ __forceinline__ void async_copy16(void* lds, const void* g) {
    __builtin_amdgcn_global_load_lds(
        (const __attribute__((address_space(1))) void*)g,
        (__attribute__((address_space(3))) void*)lds, 16, 0, 0);
}

// ---------------- fp32 -> bf16 convert (with zero padding) ----------------
__global__ __launch_bounds__(256) void cvt_bf16(const float* __restrict__ src,
                                                __bf16* __restrict__ dst,
                                                long valid4, long total4) {
    long i = (long)blockIdx.x * 256 + threadIdx.x;
    if (i >= total4) return;
    float4 f = {0.f, 0.f, 0.f, 0.f};
    if (i < valid4) f = ((const float4*)src)[i];
    __bf16 tmp[4] = {(__bf16)f.x, (__bf16)f.y, (__bf16)f.z, (__bf16)f.w};
    *((uint2*)(dst + i * 4)) = *((uint2*)tmp);
}

// ---------------- W [K][N] fp32 -> Wt [N][K] bf16 ----------------
__global__ __launch_bounds__(256) void transpose_w(const float* __restrict__ W,
                                                   __bf16* __restrict__ Wt) {
    __shared__ float tile[32][33];
    const int k0 = blockIdx.x * 32, n0 = blockIdx.y * 32;
    const int tx = threadIdx.x, ty = threadIdx.y; // 32 x 8
    #pragma unroll
    for (int i = 0; i < 32; i += 8)
        tile[ty + i][tx] = W[(long)(k0 + ty + i) * DM + n0 + tx];
    __syncthreads();
    #pragma unroll
    for (int i = 0; i < 32; i += 8)
        Wt[(long)(n0 + ty + i) * DM + k0 + tx] = (__bf16)tile[tx][ty + i];
}

// ---- V transpose: features fp32 [t][hw][1152] -> Vt bf16 [t*8+h][dh 144][col 768]
// column order PERMUTED within each 64-kv tile so attn's in-register P^T
// (from swapped QK^T) feeds the PV mfma B-operand directly.
// hw-offset bits [5]=kh,[4]=b,[3:2]=q,[1:0]=jj  ->  col bits [5]=kh,[4:3]=q,[2]=b,[1:0]=jj:
//   col(hw) = (hw & ~31) | ((hw>>2 & 3)<<3) | ((hw>>4 & 1)<<2) | (hw & 3)
__global__ __launch_bounds__(256) void transpose_v(const float* __restrict__ f,
                                                   __bf16* __restrict__ vt) {
    __shared__ float tile[32][149];
    const int hw0 = blockIdx.x * 32, h = blockIdx.y, t = blockIdx.z;
    const int tid = threadIdx.x;
    for (int c = tid; c < 32 * 36; c += 256) {
        const int r = c / 36, s = c % 36;
        const int hw = hw0 + r;
        float4 v = {0.f, 0.f, 0.f, 0.f};
        if (hw < HW_N) v = *(const float4*)(f + ((long)t * HW_N + hw) * DM + h * DH + s * 4);
        tile[r][s * 4 + 0] = v.x; tile[r][s * 4 + 1] = v.y;
        tile[r][s * 4 + 2] = v.z; tile[r][s * 4 + 3] = v.w;
    }
    __syncthreads();
    for (int c = tid; c < DH * 8; c += 256) {   // 144 d-rows x 8 granules of 4 hw
        const int d = c >> 3, g = c & 7;
        const int base4 = hw0 + g * 4;          // 4 consecutive hw, base4 % 4 == 0
        const int cb = (base4 & ~31) | (((base4 >> 2) & 3) << 3) | (((base4 >> 4) & 1) << 2);
        __bf16 tmp[4];
        #pragma unroll
        for (int i = 0; i < 4; ++i) tmp[i] = (__bf16)tile[g * 4 + i][d];
        *(uint2*)(vt + ((long)(t * NH + h) * DH + d) * HW_PV + cb) = *(uint2*)tmp;
    }
}

// ---------------- bf16 MFMA GEMM: C[M,N] = A[M,K] * Bt[N,K]^T ----------------
// 128x128 tile, BK=32, global_load_lds staging + XOR slot swizzle (conflict-free)
template<bool STORE_BF16>
__global__ __launch_bounds__(256) void gemm_bt(const __bf16* __restrict__ A,
                                               const __bf16* __restrict__ Bt,
                                               void* __restrict__ Cout) {
    __shared__ __align__(16) __bf16 As[128 * 32];
    __shared__ __align__(16) __bf16 Bs[128 * 32];
    const int tid  = threadIdx.x;
    const int wave = tid >> 6, lane = tid & 63;
    const int quad = lane >> 4, l16 = lane & 15;
    const int wr = wave >> 1, wc = wave & 1;
    const long m0 = (long)blockIdx.x * 128;
    const long n0 = (long)blockIdx.y * 128;
    const int swzr = quad ^ ((l16 >> 1) & 3);   // frag-read slot swizzle
    f32x4 acc[4][4] = {};
    for (int kt = 0; kt < 36; ++kt) {
        const int k0 = kt * 32;
        __syncthreads();
        #pragma unroll
        for (int s = 0; s < 2; ++s) {
            const int c = s * 256 + tid;        // 512 chunks of 16B each matrix
            const int row = c >> 2;
            const int gkc = (c & 3) ^ ((c >> 3) & 3);   // slot->global kc swizzle
            async_copy16(As + c * 8, A  + (m0 + row) * DM + k0 + gkc * 8);
            async_copy16(Bs + c * 8, Bt + (n0 + row) * DM + k0 + gkc * 8);
        }
        __syncthreads();
        bf16x8 af[4], bfr[4];
        #pragma unroll
        for (int i = 0; i < 4; ++i)
            af[i] = *(const bf16x8*)(As + (wr * 64 + i * 16 + l16) * 32 + swzr * 8);
        #pragma unroll
        for (int j = 0; j < 4; ++j)
            bfr[j] = *(const bf16x8*)(Bs + (wc * 64 + j * 16 + l16) * 32 + swzr * 8);
        #pragma unroll
        for (int i = 0; i < 4; ++i)
            #pragma unroll
            for (int j = 0; j < 4; ++j)
                acc[i][j] = __builtin_amdgcn_mfma_f32_16x16x32_bf16(af[i], bfr[j], acc[i][j], 0, 0, 0);
    }
    #pragma unroll
    for (int i = 0; i < 4; ++i) {
        #pragma unroll
        for (int j = 0; j < 4; ++j) {
            #pragma unroll
            for (int r = 0; r < 4; ++r) {
                const long row = m0 + wr * 64 + i * 16 + quad * 4 + r;
                const long col = n0 + wc * 64 + j * 16 + l16;
                if constexpr (STORE_BF16)
                    ((__bf16*)Cout)[row * DM + col] = (__bf16)acc[i][j][r];
                else
                    ((float*)Cout)[row * DM + col] = acc[i][j][r];
            }
        }
    }
}

// ---------------- LayerNorm (no bias) over 1152, in-place bf16 ----------------
__global__ __launch_bounds__(256) void ln_q(__bf16* __restrict__ Q, const float* __restrict__ w) {
    const long row = blockIdx.x;
    __bf16* p = Q + row * DM;
    const int tid = threadIdx.x;
    float v[5];
    int nv = 0;
    float s = 0.f, s2 = 0.f;
    for (int i = tid; i < DM; i += 256) {
        float x = (float)p[i];
        v[nv++] = x; s += x; s2 += x * x;
    }
    #pragma unroll
    for (int o = 32; o > 0; o >>= 1) { s += __shfl_down(s, o); s2 += __shfl_down(s2, o); }
    __shared__ float red[8];
    if ((tid & 63) == 0) { red[tid >> 6] = s; red[4 + (tid >> 6)] = s2; }
    __syncthreads();
    const float S  = red[0] + red[1] + red[2] + red[3];
    const float S2 = red[4] + red[5] + red[6] + red[7];
    const float mu  = S * (1.f / DM);
    const float var = S2 * (1.f / DM) - mu * mu;
    const float rstd = rsqrtf(var + 1e-6f);
    nv = 0;
    for (int i = tid; i < DM; i += 256)
        p[i] = (__bf16)((v[nv++] - mu) * rstd * w[i]);
}

// ---------------- RoPE-2D (full 1152 dim) + LayerNorm, in-place bf16 ----------------
__global__ __launch_bounds__(256) void rope_ln_k(__bf16* __restrict__ K,
                                                 const float* __restrict__ fpos,
                                                 const float* __restrict__ w) {
    const long row = blockIdx.x;            // 0..46655 = t*729+hw
    const int hw = (int)(row % HW_N);
    const float px = fpos[hw * 2 + 0];
    const float py = fpos[hw * 2 + 1];
    __bf16* p = K + row * DM;
    __shared__ float buf[DM];
    __shared__ float red[8];
    const int tid = threadIdx.x;
    float s = 0.f, s2 = 0.f;
    for (int pr = tid; pr < 576; pr += 256) {   // 288 x-pairs then 288 y-pairs
        const bool isx = pr < 288;
        const int  i   = isx ? pr : pr - 288;
        const int  off = isx ? 2 * i : 576 + 2 * i;
        const float pos = isx ? px : py;
        const float theta = exp2f((float)i * -0.046137890206768924f); // 10000^(-i/288)
        float sn, cs;
        sincosf(pos * theta, &sn, &cs);
        const float a = (float)p[off], b = (float)p[off + 1];
        const float o1 = a * cs - b * sn;
        const float o2 = a * sn + b * cs;
        buf[off] = o1; buf[off + 1] = o2;
        s += o1 + o2; s2 += o1 * o1 + o2 * o2;
    }
    #pragma unroll
    for (int o = 32; o > 0; o >>= 1) { s += __shfl_down(s, o); s2 += __shfl_down(s2, o); }
    if ((tid & 63) == 0) { red[tid >> 6] = s; red[4 + (tid >> 6)] = s2; }
    __syncthreads();
    const float S  = red[0] + red[1] + red[2] + red[3];
    const float S2 = red[4] + red[5] + red[6] + red[7];
    const float mu  = S * (1.f / DM);
    const float var = S2 * (1.f / DM) - mu * mu;
    const float rstd = rsqrtf(var + 1e-6f);
    for (int i = tid; i < DM; i += 256)
        p[i] = (__bf16)((buf[i] - mu) * rstd * w[i]);
}

// ---------------- flash attention + gaussian spatial bias ----------------
// Swapped-operand QK^T (S^T in regs) -> in-register softmax (2 shfl/row-reduce)
// -> P packed lane-locally as PV B-frags (V columns pre-permuted in Vt).
// V tile staged in LDS (coalesced async), 2 barriers/tile.
// Epilogue transposed through wave-local LDS -> coalesced 16B stores.
__global__ __launch_bounds__(256, 4) void attn(const __bf16* __restrict__ Qn,
                                               const __bf16* __restrict__ Kn,
                                               const __bf16* __restrict__ Vt,
                                               const float* __restrict__ tracks,
                                               const float* __restrict__ fpos,
                                               __bf16* __restrict__ Out) {
    // union: VtL [144][72] bf16 (20736 B) during loop; epi [4][32][152] bf16 (38912 B) after
    __shared__ __align__(16) char smem[38912];
    __bf16* VtL = (__bf16*)smem;

    const int i  = blockIdx.x;
    const int g  = ((i >> 5) << 3) | (i & 7);   // (t,h) group 0..511
    const int qt = (i >> 3) & 3;                // q-tile 0..3
    const int h  = g & 7, t = g >> 3;
    const int tid = threadIdx.x;
    const int wave = tid >> 6, lane = tid & 63;
    const int quad = lane >> 4, l16 = lane & 15;
    const int wq = wave * 32;                   // wave's q-row base within block

    const __bf16* qb = Qn + ((long)t * M_N + qt * 128 + wq) * DM + h * DH;
    const __bf16* kb = Kn + (long)t * HW_N * DM + h * DH;
    const __bf16* vb = Vt + (long)(t * NH + h) * DH * HW_PV;

    // per-lane track (this lane's q-row = l16 within each rt tile)
    float tx[2], ty[2];
    #pragma unroll
    for (int rt = 0; rt < 2; ++rt) {
        const float2 tr = ((const float2*)tracks)[(long)t * M_N + qt * 128 + wq + rt * 16 + l16];
        tx[rt] = tr.x; ty[rt] = tr.y;
    }

    f32x4 Ot[2][9] = {};
    float mrow[2] = {-1e30f, -1e30f}, lrow[2] = {0.f, 0.f};

    for (int kt = 0; kt < 12; ++kt) {
        const int kv0 = kt * 64;
        __syncthreads();                        // VtL overwrite guard
        // stage V^T tile [144][64] (+8 pad, contents unused): coalesced async
        for (int c = tid; c < DH * 9; c += 256) {
            const int r = c / 9, s = c % 9;
            const __bf16* gsrc = (s < 8) ? vb + (long)r * HW_PV + kv0 + s * 8 : vb;
            async_copy16(VtL + c * 8, gsrc);
        }
        // --- S^T = (K Q^T): sc[rt][jt] tile [kv 16][q 16]; lane col=q(l16), row=kv(quad*4+r)
        f32x4 sc[2][4] = {};
        #pragma unroll
        for (int kc = 0; kc < 5; ++kc) {
            bf16x8 bq[2];
            #pragma unroll
            for (int rt = 0; rt < 2; ++rt) {
                uint4 u = {0u, 0u, 0u, 0u};
                if (kc < 4 || quad < 2)
                    u = *(const uint4*)(qb + (long)(rt * 16 + l16) * DM + kc * 32 + quad * 8);
                bq[rt] = *(bf16x8*)&u;
            }
            #pragma unroll
            for (int jt = 0; jt < 4; ++jt) {
                const bf16x8 ak = *(const bf16x8*)(kb + (long)(kv0 + jt * 16 + l16) * DM + kc * 32 + quad * 8);
                #pragma unroll
                for (int rt = 0; rt < 2; ++rt)
                    sc[rt][jt] = __builtin_amdgcn_mfma_f32_16x16x32_bf16(ak, bq[rt], sc[rt][jt], 0, 0, 0);
            }
        }
        // --- gaussian bias + mask (lane kv = kv0 + jt*16 + quad*4 + r) ---
        #pragma unroll
        for (int jt = 0; jt < 4; ++jt) {
            const int kvb = kv0 + jt * 16 + quad * 4;
            float2 fp[4];
            if (kvb + 3 < HW_N) {
                const float4 a  = *(const float4*)(fpos + (long)kvb * 2);
                const float4 b2 = *(const float4*)(fpos + (long)kvb * 2 + 4);
                fp[0] = {a.x, a.y};  fp[1] = {a.z, a.w};
                fp[2] = {b2.x, b2.y}; fp[3] = {b2.z, b2.w};
            } else {
                #pragma unroll
                for (int r = 0; r < 4; ++r) {
                    const int k2 = (kvb + r < HW_N) ? kvb + r : HW_N - 1;
                    fp[r] = ((const float2*)fpos)[k2];
                }
            }
            #pragma unroll
            for (int rt = 0; rt < 2; ++rt)
                #pragma unroll
                for (int r = 0; r < 4; ++r) {
                    const float dx = tx[rt] - fp[r].x, dy = ty[rt] - fp[r].y;
                    float v = sc[rt][jt][r] * (1.f / 12.f) - (dx * dx + dy * dy) * 0.125f;
                    if (kvb + r >= HW_N) v = -1e30f;
                    sc[rt][jt][r] = v;
                }
        }
        // --- online softmax (per-lane row; cross-quad via 2 shfl) ---
        #pragma unroll
        for (int rt = 0; rt < 2; ++rt) {
            float mp = -1e30f;
            #pragma unroll
            for (int jt = 0; jt < 4; ++jt)
                #pragma unroll
                for (int r = 0; r < 4; ++r) mp = fmaxf(mp, sc[rt][jt][r]);
            mp = fmaxf(mp, __shfl_xor(mp, 16));
            mp = fmaxf(mp, __shfl_xor(mp, 32));
            const float mn = fmaxf(mrow[rt], mp);
            const float al = __expf(mrow[rt] - mn);
            mrow[rt] = mn;
            float rs = 0.f;
            #pragma unroll
            for (int jt = 0; jt < 4; ++jt)
                #pragma unroll
                for (int r = 0; r < 4; ++r) {
                    const float p = __expf(sc[rt][jt][r] - mn);
                    sc[rt][jt][r] = p;
                    rs += p;
                }
            rs += __shfl_xor(rs, 16);
            rs += __shfl_xor(rs, 32);
            lrow[rt] = lrow[rt] * al + rs;
            #pragma unroll
            for (int d = 0; d < 9; ++d) Ot[rt][d] *= al;
        }
        __syncthreads();                        // staging landed (barrier drains vmcnt)
        // --- O^T += V^T P^T: A-frag from LDS, B-frag lane-local P pack ---
        #pragma unroll
        for (int kh = 0; kh < 2; ++kh) {
            bf16x8 bp[2];
            #pragma unroll
            for (int rt = 0; rt < 2; ++rt) {
                __bf16 tmp[8];
                #pragma unroll
                for (int j = 0; j < 4; ++j) {
                    tmp[j]     = (__bf16)sc[rt][2 * kh][j];
                    tmp[4 + j] = (__bf16)sc[rt][2 * kh + 1][j];
                }
                bp[rt] = *(bf16x8*)tmp;
            }
            #pragma unroll
            for (int dt = 0; dt < 9; ++dt) {
                const bf16x8 av = *(const bf16x8*)(VtL + (dt * 16 + l16) * 72 + kh * 32 + quad * 8);
                #pragma unroll
                for (int rt = 0; rt < 2; ++rt)
                    Ot[rt][dt] = __builtin_amdgcn_mfma_f32_16x16x32_bf16(av, bp[rt], Ot[rt][dt], 0, 0, 0);
            }
        }
    }
    // ---- epilogue: transpose O^T via wave-local LDS -> coalesced 16B stores ----
    __syncthreads();                            // smem reuse guard (VtL dead)
    __bf16* ep = (__bf16*)smem + (size_t)wave * 32 * 152;
    #pragma unroll
    for (int rt = 0; rt < 2; ++rt) {
        const float inv = 1.f / lrow[rt];
        #pragma unroll
        for (int dt = 0; dt < 9; ++dt) {
            __bf16 o4[4];
            #pragma unroll
            for (int r = 0; r < 4; ++r) o4[r] = (__bf16)(Ot[rt][dt][r] * inv);
            *(uint2*)(ep + (rt * 16 + l16) * 152 + dt * 16 + quad * 4) = *(uint2*)o4;
        }
    }
    __syncthreads();                            // cross-lane LDS visibility
    const long rb = (long)t * M_N + qt * 128 + wq;
    #pragma unroll
    for (int c = lane; c < 576; c += 64) {      // 32 rows x 18 chunks of 16B
        const int r = c / 18, s = c % 18;
        const uint4 val = *(const uint4*)(ep + r * 152 + s * 8);
        *(uint4*)(Out + (rb + r) * DM + h * DH + s * 8) = val;
    }
}

extern "C" void kernel_launch(void* const* d_in, const int* in_sizes, int n_in,
                              void* d_out, int out_size, void* d_ws, size_t ws_size,
                              hipStream_t stream) {
    const float* features = (const float*)d_in[0];
    const float* tracks   = (const float*)d_in[1];
    const float* tok      = (const float*)d_in[2];
    const float* fpos     = (const float*)d_in[3];
    const float* W_q      = (const float*)d_in[4];
    const float* W_k      = (const float*)d_in[5];
    const float* q_w      = (const float*)d_in[6];
    const float* k_w      = (const float*)d_in[7];
    const float* W_o      = (const float*)d_in[8];

    if (ws_size < WS_NEED) return; // failure signature: absmax == max|ref|

    char* ws = (char*)d_ws;
    __bf16* kn      = (__bf16*)(ws + OFF_KN);
    __bf16* tok_bf  = (__bf16*)(ws + OFF_TOK);  // reused as `sampled` after Q-proj
    __bf16* qn      = (__bf16*)(ws + OFF_QN);
    __bf16* feat_bf = (__bf16*)(ws + OFF_OV);   // overlay: feat_bf then Vt
    __bf16* vt      = (__bf16*)(ws + OFF_OV);
    __bf16* wt_q    = (__bf16*)(ws + OFF_WT);
    __bf16* wt_k    = (__bf16*)(ws + OFF_WT + SZ_W);
    __bf16* wt_o    = (__bf16*)(ws + OFF_WT + 2 * SZ_W);

    // converts (features zero-padded to MK_PAD rows)
    {
        const long valid4 = (long)MK * DM / 4, total4 = (long)MK_PAD * DM / 4;
        cvt_bf16<<<(int)((total4 + 255) / 256), 256, 0, stream>>>(features, feat_bf, valid4, total4);
    }
    {
        const long n4 = (long)MQ * DM / 4;
        cvt_bf16<<<(int)((n4 + 255) / 256), 256, 0, stream>>>(tok, tok_bf, n4, n4);
    }
    // weight transposes
    dim3 tb(32, 8);
    transpose_w<<<dim3(36, 36), tb, 0, stream>>>(W_q, wt_q);
    transpose_w<<<dim3(36, 36), tb, 0, stream>>>(W_k, wt_k);
    transpose_w<<<dim3(36, 36), tb, 0, stream>>>(W_o, wt_o);

    // projections
    gemm_bt<true><<<dim3(MQ / 128, DM / 128), 256, 0, stream>>>(tok_bf, wt_q, qn);
    gemm_bt<true><<<dim3(MK_PAD / 128, DM / 128), 256, 0, stream>>>(feat_bf, wt_k, kn);

    // norms (+RoPE for K)
    ln_q<<<MQ, 256, 0, stream>>>(qn, q_w);
    rope_ln_k<<<MK, 256, 0, stream>>>(kn, fpos, k_w);

    // V transpose (overwrites feat_bf overlay — feat_bf dead after K-proj)
    transpose_v<<<dim3(HW_PV / 32, NH, T_N), 256, 0, stream>>>(features, vt);

    // attention -> sampled (reuses tok_bf region)
    __bf16* sampled = tok_bf;
    attn<<<T_N * NH * (M_N / 128), 256, 0, stream>>>(qn, kn, vt, tracks, fpos, sampled);

    // output projection -> d_out (fp32)
    gemm_bt<false><<<dim3(MQ / 128, DM / 128), 256, 0, stream>>>(sampled, wt_o, d_out);
}

// Round 6
// 1766.405 us; speedup vs baseline: 1.1287x; 1.1160x over previous
//
#include <hip/hip_runtime.h>
#include <hip/hip_bf16.h>
#include <math.h>

typedef float f32x4 __attribute__((ext_vector_type(4)));
typedef __bf16 bf16x8 __attribute__((ext_vector_type(8)));

#define T_N 64
#define HW_N 729
#define HW_PV 768       /* padded hw for Vt: 12 full kv-tiles of 64 */
#define M_N 512
#define DM 1152
#define NH 8
#define DH 144
#define MQ 32768        /* T*M rows */
#define MK 46656        /* T*HW rows */
#define MK_PAD 46720    /* padded to multiple of 128 (365 tiles) */

// ---- workspace layout (bytes); Vt overlays feat_bf (dead after K-proj) ----
#define SZ_FEAT ((size_t)MK_PAD * DM * 2)
#define SZ_VT   ((size_t)T_N * NH * DH * HW_PV * 2)
#define SZ_OV   (SZ_VT > SZ_FEAT ? SZ_VT : SZ_FEAT)
#define SZ_Q    ((size_t)MQ * DM * 2)
#define SZ_W    ((size_t)DM * DM * 2)
#define OFF_KN   ((size_t)0)
#define OFF_TOK  (OFF_KN + SZ_FEAT)
#define OFF_QN   (OFF_TOK + SZ_Q)
#define OFF_OV   (OFF_QN + SZ_Q)
#define OFF_WT   (OFF_OV + SZ_OV)
#define WS_NEED  (OFF_WT + 3 * SZ_W)

// async global->LDS 16B (wave-uniform base + lane*16 placement)
__device__ __forceinline__ void async_copy16(void* lds, const void* g) {
    __builtin_amdgcn_global_load_lds(
        (const __attribute__((address_space(1))) void*)g,
        (__attribute__((address_space(3))) void*)lds, 16, 0, 0);
}

// ---------------- fp32 -> bf16 convert (with zero padding) ----------------
__global__ __launch_bounds__(256) void cvt_bf16(const float* __restrict__ src,
                                                __bf16* __restrict__ dst,
                                                long valid4, long total4) {
    long i = (long)blockIdx.x * 256 + threadIdx.x;
    if (i >= total4) return;
    float4 f = {0.f, 0.f, 0.f, 0.f};
    if (i < valid4) f = ((const float4*)src)[i];
    __bf16 tmp[4] = {(__bf16)f.x, (__bf16)f.y, (__bf16)f.z, (__bf16)f.w};
    *((uint2*)(dst + i * 4)) = *((uint2*)tmp);
}

// ---------------- W [K][N] fp32 -> Wt [N][K] bf16 ----------------
__global__ __launch_bounds__(256) void transpose_w(const float* __restrict__ W,
                                                   __bf16* __restrict__ Wt) {
    __shared__ float tile[32][33];
    const int k0 = blockIdx.x * 32, n0 = blockIdx.y * 32;
    const int tx = threadIdx.x, ty = threadIdx.y; // 32 x 8
    #pragma unroll
    for (int i = 0; i < 32; i += 8)
        tile[ty + i][tx] = W[(long)(k0 + ty + i) * DM + n0 + tx];
    __syncthreads();
    #pragma unroll
    for (int i = 0; i < 32; i += 8)
        Wt[(long)(n0 + ty + i) * DM + k0 + tx] = (__bf16)tile[tx][ty + i];
}

// ---- V transpose: features fp32 [t][hw][1152] -> Vt bf16 [t*8+h][dh 144][col 768]
// column order PERMUTED within each 64-kv tile so attn's in-register P^T
// (from swapped QK^T) feeds the PV mfma B-operand directly.
// hw-offset bits [5]=kh,[4]=b,[3:2]=q,[1:0]=jj  ->  col bits [5]=kh,[4:3]=q,[2]=b,[1:0]=jj:
//   col(hw) = (hw & ~31) | ((hw>>2 & 3)<<3) | ((hw>>4 & 1)<<2) | (hw & 3)
__global__ __launch_bounds__(256) void transpose_v(const float* __restrict__ f,
                                                   __bf16* __restrict__ vt) {
    __shared__ float tile[32][149];
    const int hw0 = blockIdx.x * 32, h = blockIdx.y, t = blockIdx.z;
    const int tid = threadIdx.x;
    for (int c = tid; c < 32 * 36; c += 256) {
        const int r = c / 36, s = c % 36;
        const int hw = hw0 + r;
        float4 v = {0.f, 0.f, 0.f, 0.f};
        if (hw < HW_N) v = *(const float4*)(f + ((long)t * HW_N + hw) * DM + h * DH + s * 4);
        tile[r][s * 4 + 0] = v.x; tile[r][s * 4 + 1] = v.y;
        tile[r][s * 4 + 2] = v.z; tile[r][s * 4 + 3] = v.w;
    }
    __syncthreads();
    for (int c = tid; c < DH * 8; c += 256) {   // 144 d-rows x 8 granules of 4 hw
        const int d = c >> 3, g = c & 7;
        const int base4 = hw0 + g * 4;          // 4 consecutive hw, base4 % 4 == 0
        const int cb = (base4 & ~31) | (((base4 >> 2) & 3) << 3) | (((base4 >> 4) & 1) << 2);
        __bf16 tmp[4];
        #pragma unroll
        for (int i = 0; i < 4; ++i) tmp[i] = (__bf16)tile[g * 4 + i][d];
        *(uint2*)(vt + ((long)(t * NH + h) * DH + d) * HW_PV + cb) = *(uint2*)tmp;
    }
}

// ---------------- bf16 MFMA GEMM: C[M,N] = A[M,K] * Bt[N,K]^T ----------------
// 128x128 tile, BK=32, global_load_lds staging + XOR slot swizzle (conflict-free)
template<bool STORE_BF16>
__global__ __launch_bounds__(256) void gemm_bt(const __bf16* __restrict__ A,
                                               const __bf16* __restrict__ Bt,
                                               void* __restrict__ Cout) {
    __shared__ __align__(16) __bf16 As[128 * 32];
    __shared__ __align__(16) __bf16 Bs[128 * 32];
    const int tid  = threadIdx.x;
    const int wave = tid >> 6, lane = tid & 63;
    const int quad = lane >> 4, l16 = lane & 15;
    const int wr = wave >> 1, wc = wave & 1;
    const long m0 = (long)blockIdx.x * 128;
    const long n0 = (long)blockIdx.y * 128;
    const int swzr = quad ^ ((l16 >> 1) & 3);   // frag-read slot swizzle
    f32x4 acc[4][4] = {};
    for (int kt = 0; kt < 36; ++kt) {
        const int k0 = kt * 32;
        __syncthreads();
        #pragma unroll
        for (int s = 0; s < 2; ++s) {
            const int c = s * 256 + tid;        // 512 chunks of 16B each matrix
            const int row = c >> 2;
            const int gkc = (c & 3) ^ ((c >> 3) & 3);   // slot->global kc swizzle
            async_copy16(As + c * 8, A  + (m0 + row) * DM + k0 + gkc * 8);
            async_copy16(Bs + c * 8, Bt + (n0 + row) * DM + k0 + gkc * 8);
        }
        __syncthreads();
        bf16x8 af[4], bfr[4];
        #pragma unroll
        for (int i = 0; i < 4; ++i)
            af[i] = *(const bf16x8*)(As + (wr * 64 + i * 16 + l16) * 32 + swzr * 8);
        #pragma unroll
        for (int j = 0; j < 4; ++j)
            bfr[j] = *(const bf16x8*)(Bs + (wc * 64 + j * 16 + l16) * 32 + swzr * 8);
        #pragma unroll
        for (int i = 0; i < 4; ++i)
            #pragma unroll
            for (int j = 0; j < 4; ++j)
                acc[i][j] = __builtin_amdgcn_mfma_f32_16x16x32_bf16(af[i], bfr[j], acc[i][j], 0, 0, 0);
    }
    #pragma unroll
    for (int i = 0; i < 4; ++i) {
        #pragma unroll
        for (int j = 0; j < 4; ++j) {
            #pragma unroll
            for (int r = 0; r < 4; ++r) {
                const long row = m0 + wr * 64 + i * 16 + quad * 4 + r;
                const long col = n0 + wc * 64 + j * 16 + l16;
                if constexpr (STORE_BF16)
                    ((__bf16*)Cout)[row * DM + col] = (__bf16)acc[i][j][r];
                else
                    ((float*)Cout)[row * DM + col] = acc[i][j][r];
            }
        }
    }
}

// ---------------- LayerNorm (no bias) over 1152, in-place bf16 ----------------
__global__ __launch_bounds__(256) void ln_q(__bf16* __restrict__ Q, const float* __restrict__ w) {
    const long row = blockIdx.x;
    __bf16* p = Q + row * DM;
    const int tid = threadIdx.x;
    float v[5];
    int nv = 0;
    float s = 0.f, s2 = 0.f;
    for (int i = tid; i < DM; i += 256) {
        float x = (float)p[i];
        v[nv++] = x; s += x; s2 += x * x;
    }
    #pragma unroll
    for (int o = 32; o > 0; o >>= 1) { s += __shfl_down(s, o); s2 += __shfl_down(s2, o); }
    __shared__ float red[8];
    if ((tid & 63) == 0) { red[tid >> 6] = s; red[4 + (tid >> 6)] = s2; }
    __syncthreads();
    const float S  = red[0] + red[1] + red[2] + red[3];
    const float S2 = red[4] + red[5] + red[6] + red[7];
    const float mu  = S * (1.f / DM);
    const float var = S2 * (1.f / DM) - mu * mu;
    const float rstd = rsqrtf(var + 1e-6f);
    nv = 0;
    for (int i = tid; i < DM; i += 256)
        p[i] = (__bf16)((v[nv++] - mu) * rstd * w[i]);
}

// ---------------- RoPE-2D (full 1152 dim) + LayerNorm, in-place bf16 ----------------
__global__ __launch_bounds__(256) void rope_ln_k(__bf16* __restrict__ K,
                                                 const float* __restrict__ fpos,
                                                 const float* __restrict__ w) {
    const long row = blockIdx.x;            // 0..46655 = t*729+hw
    const int hw = (int)(row % HW_N);
    const float px = fpos[hw * 2 + 0];
    const float py = fpos[hw * 2 + 1];
    __bf16* p = K + row * DM;
    __shared__ float buf[DM];
    __shared__ float red[8];
    const int tid = threadIdx.x;
    float s = 0.f, s2 = 0.f;
    for (int pr = tid; pr < 576; pr += 256) {   // 288 x-pairs then 288 y-pairs
        const bool isx = pr < 288;
        const int  i   = isx ? pr : pr - 288;
        const int  off = isx ? 2 * i : 576 + 2 * i;
        const float pos = isx ? px : py;
        const float theta = exp2f((float)i * -0.046137890206768924f); // 10000^(-i/288)
        float sn, cs;
        sincosf(pos * theta, &sn, &cs);
        const float a = (float)p[off], b = (float)p[off + 1];
        const float o1 = a * cs - b * sn;
        const float o2 = a * sn + b * cs;
        buf[off] = o1; buf[off + 1] = o2;
        s += o1 + o2; s2 += o1 * o1 + o2 * o2;
    }
    #pragma unroll
    for (int o = 32; o > 0; o >>= 1) { s += __shfl_down(s, o); s2 += __shfl_down(s2, o); }
    if ((tid & 63) == 0) { red[tid >> 6] = s; red[4 + (tid >> 6)] = s2; }
    __syncthreads();
    const float S  = red[0] + red[1] + red[2] + red[3];
    const float S2 = red[4] + red[5] + red[6] + red[7];
    const float mu  = S * (1.f / DM);
    const float var = S2 * (1.f / DM) - mu * mu;
    const float rstd = rsqrtf(var + 1e-6f);
    for (int i = tid; i < DM; i += 256)
        p[i] = (__bf16)((buf[i] - mu) * rstd * w[i]);
}

// ---------------- flash attention + gaussian spatial bias ----------------
// Swapped-operand QK^T (S^T in regs) -> in-register softmax (2 shfl/row-reduce)
// -> P packed lane-locally as PV B-frags (V columns pre-permuted in Vt).
// V tile staged in LDS (coalesced async), 2 barriers/tile.
// Epilogue transposed through wave-local LDS -> coalesced 16B stores.
// launch_bounds (256,3): VGPR cap ~170 — do NOT tighten; (256,4) forced
// accumulator spills to scratch (+1 GB HBM writes, round-4 post-mortem).
__global__ __launch_bounds__(256, 3) void attn(const __bf16* __restrict__ Qn,
                                               const __bf16* __restrict__ Kn,
                                               const __bf16* __restrict__ Vt,
                                               const float* __restrict__ tracks,
                                               const float* __restrict__ fpos,
                                               __bf16* __restrict__ Out) {
    // union: VtL [144][72] bf16 (20736 B) during loop; epi [4][32][152] bf16 (38912 B) after
    __shared__ __align__(16) char smem[38912];
    __bf16* VtL = (__bf16*)smem;

    const int i  = blockIdx.x;
    const int g  = ((i >> 5) << 3) | (i & 7);   // (t,h) group 0..511
    const int qt = (i >> 3) & 3;                // q-tile 0..3
    const int h  = g & 7, t = g >> 3;
    const int tid = threadIdx.x;
    const int wave = tid >> 6, lane = tid & 63;
    const int quad = lane >> 4, l16 = lane & 15;
    const int wq = wave * 32;                   // wave's q-row base within block

    const __bf16* qb = Qn + ((long)t * M_N + qt * 128 + wq) * DM + h * DH;
    const __bf16* kb = Kn + (long)t * HW_N * DM + h * DH;
    const __bf16* vb = Vt + (long)(t * NH + h) * DH * HW_PV;

    // per-lane track (this lane's q-row = l16 within each rt tile)
    float tx[2], ty[2];
    #pragma unroll
    for (int rt = 0; rt < 2; ++rt) {
        const float2 tr = ((const float2*)tracks)[(long)t * M_N + qt * 128 + wq + rt * 16 + l16];
        tx[rt] = tr.x; ty[rt] = tr.y;
    }

    f32x4 Ot[2][9] = {};
    float mrow[2] = {-1e30f, -1e30f}, lrow[2] = {0.f, 0.f};

    for (int kt = 0; kt < 12; ++kt) {
        const int kv0 = kt * 64;
        __syncthreads();                        // VtL overwrite guard
        // stage V^T tile [144][64] (+8 pad, contents unused): coalesced async
        for (int c = tid; c < DH * 9; c += 256) {
            const int r = c / 9, s = c % 9;
            const __bf16* gsrc = (s < 8) ? vb + (long)r * HW_PV + kv0 + s * 8 : vb;
            async_copy16(VtL + c * 8, gsrc);
        }
        // --- S^T = (K Q^T): sc[rt][jt] tile [kv 16][q 16]; lane col=q(l16), row=kv(quad*4+r)
        f32x4 sc[2][4] = {};
        #pragma unroll
        for (int kc = 0; kc < 5; ++kc) {
            bf16x8 bq[2];
            #pragma unroll
            for (int rt = 0; rt < 2; ++rt) {
                uint4 u = {0u, 0u, 0u, 0u};
                if (kc < 4 || quad < 2)
                    u = *(const uint4*)(qb + (long)(rt * 16 + l16) * DM + kc * 32 + quad * 8);
                bq[rt] = *(bf16x8*)&u;
            }
            #pragma unroll
            for (int jt = 0; jt < 4; ++jt) {
                const bf16x8 ak = *(const bf16x8*)(kb + (long)(kv0 + jt * 16 + l16) * DM + kc * 32 + quad * 8);
                #pragma unroll
                for (int rt = 0; rt < 2; ++rt)
                    sc[rt][jt] = __builtin_amdgcn_mfma_f32_16x16x32_bf16(ak, bq[rt], sc[rt][jt], 0, 0, 0);
            }
        }
        // --- gaussian bias + mask (lane kv = kv0 + jt*16 + quad*4 + r) ---
        #pragma unroll
        for (int jt = 0; jt < 4; ++jt) {
            const int kvb = kv0 + jt * 16 + quad * 4;
            float2 fp[4];
            if (kvb + 3 < HW_N) {
                const float4 a  = *(const float4*)(fpos + (long)kvb * 2);
                const float4 b2 = *(const float4*)(fpos + (long)kvb * 2 + 4);
                fp[0] = {a.x, a.y};  fp[1] = {a.z, a.w};
                fp[2] = {b2.x, b2.y}; fp[3] = {b2.z, b2.w};
            } else {
                #pragma unroll
                for (int r = 0; r < 4; ++r) {
                    const int k2 = (kvb + r < HW_N) ? kvb + r : HW_N - 1;
                    fp[r] = ((const float2*)fpos)[k2];
                }
            }
            #pragma unroll
            for (int rt = 0; rt < 2; ++rt)
                #pragma unroll
                for (int r = 0; r < 4; ++r) {
                    const float dx = tx[rt] - fp[r].x, dy = ty[rt] - fp[r].y;
                    float v = sc[rt][jt][r] * (1.f / 12.f) - (dx * dx + dy * dy) * 0.125f;
                    if (kvb + r >= HW_N) v = -1e30f;
                    sc[rt][jt][r] = v;
                }
        }
        // --- online softmax (per-lane row; cross-quad via 2 shfl) ---
        #pragma unroll
        for (int rt = 0; rt < 2; ++rt) {
            float mp = -1e30f;
            #pragma unroll
            for (int jt = 0; jt < 4; ++jt)
                #pragma unroll
                for (int r = 0; r < 4; ++r) mp = fmaxf(mp, sc[rt][jt][r]);
            mp = fmaxf(mp, __shfl_xor(mp, 16));
            mp = fmaxf(mp, __shfl_xor(mp, 32));
            const float mn = fmaxf(mrow[rt], mp);
            const float al = __expf(mrow[rt] - mn);
            mrow[rt] = mn;
            float rs = 0.f;
            #pragma unroll
            for (int jt = 0; jt < 4; ++jt)
                #pragma unroll
                for (int r = 0; r < 4; ++r) {
                    const float p = __expf(sc[rt][jt][r] - mn);
                    sc[rt][jt][r] = p;
                    rs += p;
                }
            rs += __shfl_xor(rs, 16);
            rs += __shfl_xor(rs, 32);
            lrow[rt] = lrow[rt] * al + rs;
            #pragma unroll
            for (int d = 0; d < 9; ++d) Ot[rt][d] *= al;
        }
        __syncthreads();                        // staging landed (barrier drains vmcnt)
        // --- O^T += V^T P^T: A-frag from LDS, B-frag lane-local P pack ---
        #pragma unroll
        for (int kh = 0; kh < 2; ++kh) {
            bf16x8 bp[2];
            #pragma unroll
            for (int rt = 0; rt < 2; ++rt) {
                __bf16 tmp[8];
                #pragma unroll
                for (int j = 0; j < 4; ++j) {
                    tmp[j]     = (__bf16)sc[rt][2 * kh][j];
                    tmp[4 + j] = (__bf16)sc[rt][2 * kh + 1][j];
                }
                bp[rt] = *(bf16x8*)tmp;
            }
            #pragma unroll
            for (int dt = 0; dt < 9; ++dt) {
                const bf16x8 av = *(const bf16x8*)(VtL + (dt * 16 + l16) * 72 + kh * 32 + quad * 8);
                #pragma unroll
                for (int rt = 0; rt < 2; ++rt)
                    Ot[rt][dt] = __builtin_amdgcn_mfma_f32_16x16x32_bf16(av, bp[rt], Ot[rt][dt], 0, 0, 0);
            }
        }
    }
    // ---- epilogue: transpose O^T via wave-local LDS -> coalesced 16B stores ----
    __syncthreads();                            // smem reuse guard (VtL dead)
    __bf16* ep = (__bf16*)smem + (size_t)wave * 32 * 152;
    #pragma unroll
    for (int rt = 0; rt < 2; ++rt) {
        const float inv = 1.f / lrow[rt];
        #pragma unroll
        for (int dt = 0; dt < 9; ++dt) {
            __bf16 o4[4];
            #pragma unroll
            for (int r = 0; r < 4; ++r) o4[r] = (__bf16)(Ot[rt][dt][r] * inv);
            *(uint2*)(ep + (rt * 16 + l16) * 152 + dt * 16 + quad * 4) = *(uint2*)o4;
        }
    }
    __syncthreads();                            // cross-lane LDS visibility
    const long rb = (long)t * M_N + qt * 128 + wq;
    #pragma unroll
    for (int c = lane; c < 576; c += 64) {      // 32 rows x 18 chunks of 16B
        const int r = c / 18, s = c % 18;
        const uint4 val = *(const uint4*)(ep + r * 152 + s * 8);
        *(uint4*)(Out + (rb + r) * DM + h * DH + s * 8) = val;
    }
}

extern "C" void kernel_launch(void* const* d_in, const int* in_sizes, int n_in,
                              void* d_out, int out_size, void* d_ws, size_t ws_size,
                              hipStream_t stream) {
    const float* features = (const float*)d_in[0];
    const float* tracks   = (const float*)d_in[1];
    const float* tok      = (const float*)d_in[2];
    const float* fpos     = (const float*)d_in[3];
    const float* W_q      = (const float*)d_in[4];
    const float* W_k      = (const float*)d_in[5];
    const float* q_w      = (const float*)d_in[6];
    const float* k_w      = (const float*)d_in[7];
    const float* W_o      = (const float*)d_in[8];

    if (ws_size < WS_NEED) return; // failure signature: absmax == max|ref|

    char* ws = (char*)d_ws;
    __bf16* kn      = (__bf16*)(ws + OFF_KN);
    __bf16* tok_bf  = (__bf16*)(ws + OFF_TOK);  // reused as `sampled` after Q-proj
    __bf16* qn      = (__bf16*)(ws + OFF_QN);
    __bf16* feat_bf = (__bf16*)(ws + OFF_OV);   // overlay: feat_bf then Vt
    __bf16* vt      = (__bf16*)(ws + OFF_OV);
    __bf16* wt_q    = (__bf16*)(ws + OFF_WT);
    __bf16* wt_k    = (__bf16*)(ws + OFF_WT + SZ_W);
    __bf16* wt_o    = (__bf16*)(ws + OFF_WT + 2 * SZ_W);

    // converts (features zero-padded to MK_PAD rows)
    {
        const long valid4 = (long)MK * DM / 4, total4 = (long)MK_PAD * DM / 4;
        cvt_bf16<<<(int)((total4 + 255) / 256), 256, 0, stream>>>(features, feat_bf, valid4, total4);
    }
    {
        const long n4 = (long)MQ * DM / 4;
        cvt_bf16<<<(int)((n4 + 255) / 256), 256, 0, stream>>>(tok, tok_bf, n4, n4);
    }
    // weight transposes
    dim3 tb(32, 8);
    transpose_w<<<dim3(36, 36), tb, 0, stream>>>(W_q, wt_q);
    transpose_w<<<dim3(36, 36), tb, 0, stream>>>(W_k, wt_k);
    transpose_w<<<dim3(36, 36), tb, 0, stream>>>(W_o, wt_o);

    // projections
    gemm_bt<true><<<dim3(MQ / 128, DM / 128), 256, 0, stream>>>(tok_bf, wt_q, qn);
    gemm_bt<true><<<dim3(MK_PAD / 128, DM / 128), 256, 0, stream>>>(feat_bf, wt_k, kn);

    // norms (+RoPE for K)
    ln_q<<<MQ, 256, 0, stream>>>(qn, q_w);
    rope_ln_k<<<MK, 256, 0, stream>>>(kn, fpos, k_w);

    // V transpose (overwrites feat_bf overlay — feat_bf dead after K-proj)
    transpose_v<<<dim3(HW_PV / 32, NH, T_N), 256, 0, stream>>>(features, vt);

    // attention -> sampled (reuses tok_bf region)
    __bf16* sampled = tok_bf;
    attn<<<T_N * NH * (M_N / 128), 256, 0, stream>>>(qn, kn, vt, tracks, fpos, sampled);

    // output projection -> d_out (fp32)
    gemm_bt<false><<<dim3(MQ / 128, DM / 128), 256, 0, stream>>>(sampled, wt_o, d_out);
}